// Round 3
// baseline (144.949 us; speedup 1.0000x reference)
//
#include <hip/hip_runtime.h>
#include <hip/hip_bf16.h>

#define Bv 8
#define Tv 64
#define Nv 128
#define P2v 256
#define KSv 64

typedef __attribute__((ext_vector_type(8))) short bf8;   // 8 bf16 in 4 VGPRs
typedef __attribute__((ext_vector_type(4))) float f4;    // MFMA C/D frag

#define MFMA16(a, b, c) __builtin_amdgcn_mfma_f32_16x16x32_bf16((a), (b), (c), 0, 0, 0)

union B8U {
  bf8 v;
  short s[8];
};

__device__ __forceinline__ unsigned short f2bf(float f) {
  unsigned u = __float_as_uint(f);
  return (unsigned short)((u + 0x7fffu + ((u >> 16) & 1u)) >> 16);
}
__device__ __forceinline__ float bf2f(unsigned short h) {
  return __uint_as_float(((unsigned)h) << 16);
}

// LDS [128][64] bf16, XOR-swizzled 16B granules: elem offset
__device__ __forceinline__ int qswz(int i, int ks) {
  int gin = ks >> 3;
  return i * 64 + ((gin ^ (i & 7)) << 3) + (ks & 7);
}
// LDS [256][128] bf16 (V^T), XOR-swizzled
__device__ __forceinline__ int vswz(int q, int j) {
  int gin = j >> 3;
  return q * 128 + ((gin ^ (q & 7)) << 3) + (j & 7);
}

// ---------------------------------------------------------------------------
// Prep: W_Q, W_K -> split hi/lo bf16 fragment-linear; W_V -> bf16 frag-linear.
// ---------------------------------------------------------------------------
__global__ __launch_bounds__(256) void prep_w_kernel(
    const float* __restrict__ Wq, const float* __restrict__ Wk,
    const float* __restrict__ Wv, unsigned short* __restrict__ wqh,
    unsigned short* __restrict__ wql, unsigned short* __restrict__ wkh,
    unsigned short* __restrict__ wkl, unsigned short* __restrict__ wvf) {
  const int e = blockIdx.x * 256 + threadIdx.x;  // 0..98303
  if (e < 32768) {
    const float* W = (e < 16384) ? Wq : Wk;
    unsigned short* oh = (e < 16384) ? wqh : wkh;
    unsigned short* ol = (e < 16384) ? wql : wkl;
    const int t = e & 16383;
    const int jj = t & 7, lane = (t >> 3) & 63, nt = (t >> 9) & 3, pt = t >> 11;
    const int p = pt * 32 + 8 * (lane >> 4) + jj;
    const int n = nt * 16 + (lane & 15);
    const float v = W[p * KSv + n];
    const unsigned short h = f2bf(v);
    oh[t] = h;
    ol[t] = f2bf(v - bf2f(h));
  } else {
    const int t = e - 32768;  // 0..65535
    const int jj = t & 7, lane = (t >> 3) & 63, nt = (t >> 9) & 15, pt = t >> 13;
    const int p = pt * 32 + 8 * (lane >> 4) + jj;
    const int q = nt * 16 + (lane & 15);
    wvf[t] = f2bf(Wv[p * P2v + q]);
  }
}

// ---------------------------------------------------------------------------
// Big-path kernel A: per (b,t): Q,K (bf16x3) + V (bf16) from one X pass.
// S = Q K^T / 8 -> ws (fp32).  V^T (bf16, row-major [q][j]) -> ws.
// ---------------------------------------------------------------------------
__global__ __launch_bounds__(512) void qkv_kernel(
    const float* __restrict__ x, const unsigned short* __restrict__ wqh,
    const unsigned short* __restrict__ wql,
    const unsigned short* __restrict__ wkh,
    const unsigned short* __restrict__ wkl,
    const unsigned short* __restrict__ wvf, float* __restrict__ S,
    unsigned short* __restrict__ Vt) {
  __shared__ alignas(16) unsigned short qh_l[Nv * KSv];
  __shared__ alignas(16) unsigned short ql_l[Nv * KSv];
  __shared__ alignas(16) unsigned short kh_l[Nv * KSv];
  __shared__ alignas(16) unsigned short kl_l[Nv * KSv];
  const int bt = blockIdx.x;
  const float* __restrict__ X = x + (size_t)bt * (Nv * P2v);
  const int tid = threadIdx.x, lane = tid & 63, wid = tid >> 6;
  const int lg = lane >> 4, lr = lane & 15;
  const int r0 = wid * 16;

  const f4 zero = {0.f, 0.f, 0.f, 0.f};
  f4 aQ[4], aK[4], aV[16];
#pragma unroll
  for (int n = 0; n < 4; ++n) {
    aQ[n] = zero;
    aK[n] = zero;
  }
#pragma unroll
  for (int n = 0; n < 16; ++n) aV[n] = zero;

  // Phase 1: Q,K (x3 split) and V (bf16) projections from one X load
#pragma unroll 2
  for (int kt = 0; kt < 8; ++kt) {
    const float* xr = X + (r0 + lr) * P2v + kt * 32 + lg * 8;
    const float4 x0 = *(const float4*)(xr);
    const float4 x1 = *(const float4*)(xr + 4);
    const float xs[8] = {x0.x, x0.y, x0.z, x0.w, x1.x, x1.y, x1.z, x1.w};
    B8U xh, xl;
#pragma unroll
    for (int j = 0; j < 8; ++j) {
      const unsigned short h = f2bf(xs[j]);
      xh.s[j] = (short)h;
      xl.s[j] = (short)f2bf(xs[j] - bf2f(h));
    }
#pragma unroll
    for (int n = 0; n < 4; ++n) {
      const int o = ((kt * 4 + n) * 64 + lane) * 8;
      const bf8 fqh = *(const bf8*)(wqh + o);
      const bf8 fql = *(const bf8*)(wql + o);
      const bf8 fkh = *(const bf8*)(wkh + o);
      const bf8 fkl = *(const bf8*)(wkl + o);
      aQ[n] = MFMA16(xh.v, fqh, aQ[n]);
      aQ[n] = MFMA16(xh.v, fql, aQ[n]);
      aQ[n] = MFMA16(xl.v, fqh, aQ[n]);
      aK[n] = MFMA16(xh.v, fkh, aK[n]);
      aK[n] = MFMA16(xh.v, fkl, aK[n]);
      aK[n] = MFMA16(xl.v, fkh, aK[n]);
    }
#pragma unroll
    for (int n = 0; n < 16; ++n) {
      const int o = ((kt * 16 + n) * 64 + lane) * 8;
      const bf8 wv = *(const bf8*)(wvf + o);
      aV[n] = MFMA16(xh.v, wv, aV[n]);
    }
  }

  // V^T -> global ws, row-major [q][j], packed 4 bf16 (8B) per store.
  // lane holds V[row=r0+4lg+r][col=16n+lr] = V^T[q=16n+lr][j=r0+4lg+r]
  unsigned short* __restrict__ Vtb = Vt + (size_t)bt * (P2v * Nv);
  const int j0 = r0 + 4 * lg;
#pragma unroll
  for (int n = 0; n < 16; ++n) {
    const int q = n * 16 + lr;
    ushort4 pk;
    pk.x = f2bf(aV[n][0]);
    pk.y = f2bf(aV[n][1]);
    pk.z = f2bf(aV[n][2]);
    pk.w = f2bf(aV[n][3]);
    *(ushort4*)(Vtb + q * Nv + j0) = pk;
  }

  // Split Q,K to hi/lo bf16 in LDS (C-layout: row=4*lg+r, col=lr)
#pragma unroll
  for (int n = 0; n < 4; ++n) {
#pragma unroll
    for (int r = 0; r < 4; ++r) {
      const int i = r0 + 4 * lg + r;
      const int ks = n * 16 + lr;
      const int off = qswz(i, ks);
      const float qv = aQ[n][r], kv = aK[n][r];
      const unsigned short qh = f2bf(qv), kh = f2bf(kv);
      qh_l[off] = qh;
      ql_l[off] = f2bf(qv - bf2f(qh));
      kh_l[off] = kh;
      kl_l[off] = f2bf(kv - bf2f(kh));
    }
  }
  __syncthreads();

  // Phase 2: S = Q K^T / 8 (bf16x3)
  f4 aS[8];
#pragma unroll
  for (int n = 0; n < 8; ++n) aS[n] = zero;
#pragma unroll
  for (int kt = 0; kt < 2; ++kt) {
    const int qoff = qswz(r0 + lr, kt * 32 + lg * 8);
    const bf8 fqh = *(const bf8*)(qh_l + qoff);
    const bf8 fql = *(const bf8*)(ql_l + qoff);
#pragma unroll
    for (int n = 0; n < 8; ++n) {
      const int koff = qswz(n * 16 + lr, kt * 32 + lg * 8);
      const bf8 fkh = *(const bf8*)(kh_l + koff);
      const bf8 fkl = *(const bf8*)(kl_l + koff);
      aS[n] = MFMA16(fqh, fkh, aS[n]);
      aS[n] = MFMA16(fqh, fkl, aS[n]);
      aS[n] = MFMA16(fql, fkh, aS[n]);
    }
  }
  float* __restrict__ Sb = S + (size_t)bt * (Nv * Nv);
#pragma unroll
  for (int n = 0; n < 8; ++n) {
#pragma unroll
    for (int r = 0; r < 4; ++r) {
      Sb[(r0 + 4 * lg + r) * Nv + n * 16 + lr] = aS[n][r] * 0.125f;
    }
  }
}

// ---------------------------------------------------------------------------
// Kernel B: softmax over T axis, in place on S (fp32).
// ---------------------------------------------------------------------------
__global__ __launch_bounds__(256) void softmax_t_kernel(float* __restrict__ S) {
  const int idx = blockIdx.x * 256 + threadIdx.x;  // 0 .. B*N*N-1
  const int j = idx & (Nv - 1);
  const int i = (idx >> 7) & (Nv - 1);
  const int b = idx >> 14;
  const size_t base = ((size_t)b * Tv * Nv * Nv) + (size_t)i * Nv + j;

  float vals[Tv];
  float m = -1e30f;
#pragma unroll
  for (int t = 0; t < Tv; ++t) {
    const float v = S[base + (size_t)t * Nv * Nv];
    vals[t] = v;
    m = fmaxf(m, v);
  }
  float s = 0.f;
#pragma unroll
  for (int t = 0; t < Tv; ++t) {
    const float e = __expf(vals[t] - m);
    vals[t] = e;
    s += e;
  }
  const float inv = 1.f / s;
#pragma unroll
  for (int t = 0; t < Tv; ++t) {
    S[base + (size_t)t * Nv * Nv] = vals[t] * inv;
  }
}

// ---------------------------------------------------------------------------
// Big-path kernel C: stage V^T (bf16) from ws into swizzled LDS; out = A @ V.
// ---------------------------------------------------------------------------
__global__ __launch_bounds__(512) void av_stage_kernel(
    const float* __restrict__ A, const unsigned short* __restrict__ Vt,
    float* __restrict__ out) {
  __shared__ alignas(16) unsigned short vt[P2v * Nv];  // 64 KB
  const int bt = blockIdx.x;
  const float* __restrict__ Ab = A + (size_t)bt * (Nv * Nv);
  const unsigned short* __restrict__ Vtb = Vt + (size_t)bt * (P2v * Nv);
  float* __restrict__ ob = out + (size_t)bt * (Nv * P2v);
  const int tid = threadIdx.x, lane = tid & 63, wid = tid >> 6;
  const int lg = lane >> 4, lr = lane & 15;
  const int r0 = wid * 16;

  // Stage: 16B chunks, coalesced global read, swizzled LDS write.
#pragma unroll
  for (int it = 0; it < 8; ++it) {
    const int c = it * 512 + tid;  // chunk of 8 bf16
    const int q = c >> 4, gin = c & 15;
    const uint4 v = *(const uint4*)(Vtb + c * 8);
    *(uint4*)(vt + q * Nv + ((gin ^ (q & 7)) << 3)) = v;
  }
  __syncthreads();

  // out = A @ V  (A fp32 -> bf16 fragments on the fly)
  const f4 zero = {0.f, 0.f, 0.f, 0.f};
  f4 aO[16];
#pragma unroll
  for (int n = 0; n < 16; ++n) aO[n] = zero;
#pragma unroll
  for (int kt = 0; kt < 4; ++kt) {
    const float* ar = Ab + (r0 + lr) * Nv + kt * 32 + lg * 8;
    const float4 a0 = *(const float4*)(ar);
    const float4 a1 = *(const float4*)(ar + 4);
    const float as_[8] = {a0.x, a0.y, a0.z, a0.w, a1.x, a1.y, a1.z, a1.w};
    B8U af;
#pragma unroll
    for (int j = 0; j < 8; ++j) af.s[j] = (short)f2bf(as_[j]);
#pragma unroll
    for (int n = 0; n < 16; ++n) {
      const int voff = vswz(n * 16 + lr, kt * 32 + lg * 8);
      const bf8 vf = *(const bf8*)(vt + voff);
      aO[n] = MFMA16(af.v, vf, aO[n]);
    }
  }
#pragma unroll
  for (int n = 0; n < 16; ++n) {
#pragma unroll
    for (int r = 0; r < 4; ++r) {
      ob[(r0 + 4 * lg + r) * P2v + n * 16 + lr] = aO[n][r];
    }
  }
}

// ---------------------------------------------------------------------------
// Fallback kernels (ws too small for Vt): round-2 qk + av w/ packed V^T writes
// ---------------------------------------------------------------------------
__global__ __launch_bounds__(512) void qk_kernel(
    const float* __restrict__ x, const unsigned short* __restrict__ wqh,
    const unsigned short* __restrict__ wql,
    const unsigned short* __restrict__ wkh,
    const unsigned short* __restrict__ wkl, float* __restrict__ S) {
  __shared__ alignas(16) unsigned short qh_l[Nv * KSv];
  __shared__ alignas(16) unsigned short ql_l[Nv * KSv];
  __shared__ alignas(16) unsigned short kh_l[Nv * KSv];
  __shared__ alignas(16) unsigned short kl_l[Nv * KSv];
  const int bt = blockIdx.x;
  const float* __restrict__ X = x + (size_t)bt * (Nv * P2v);
  const int tid = threadIdx.x, lane = tid & 63, wid = tid >> 6;
  const int lg = lane >> 4, lr = lane & 15;
  const int r0 = wid * 16;

  const f4 zero = {0.f, 0.f, 0.f, 0.f};
  f4 aQ[4], aK[4];
#pragma unroll
  for (int n = 0; n < 4; ++n) {
    aQ[n] = zero;
    aK[n] = zero;
  }
#pragma unroll 2
  for (int kt = 0; kt < 8; ++kt) {
    const float* xr = X + (r0 + lr) * P2v + kt * 32 + lg * 8;
    const float4 x0 = *(const float4*)(xr);
    const float4 x1 = *(const float4*)(xr + 4);
    const float xs[8] = {x0.x, x0.y, x0.z, x0.w, x1.x, x1.y, x1.z, x1.w};
    B8U xh, xl;
#pragma unroll
    for (int j = 0; j < 8; ++j) {
      const unsigned short h = f2bf(xs[j]);
      xh.s[j] = (short)h;
      xl.s[j] = (short)f2bf(xs[j] - bf2f(h));
    }
#pragma unroll
    for (int n = 0; n < 4; ++n) {
      const int o = ((kt * 4 + n) * 64 + lane) * 8;
      const bf8 fqh = *(const bf8*)(wqh + o);
      const bf8 fql = *(const bf8*)(wql + o);
      const bf8 fkh = *(const bf8*)(wkh + o);
      const bf8 fkl = *(const bf8*)(wkl + o);
      aQ[n] = MFMA16(xh.v, fqh, aQ[n]);
      aQ[n] = MFMA16(xh.v, fql, aQ[n]);
      aQ[n] = MFMA16(xl.v, fqh, aQ[n]);
      aK[n] = MFMA16(xh.v, fkh, aK[n]);
      aK[n] = MFMA16(xh.v, fkl, aK[n]);
      aK[n] = MFMA16(xl.v, fkh, aK[n]);
    }
  }
#pragma unroll
  for (int n = 0; n < 4; ++n) {
#pragma unroll
    for (int r = 0; r < 4; ++r) {
      const int i = r0 + 4 * lg + r;
      const int ks = n * 16 + lr;
      const int off = qswz(i, ks);
      const float qv = aQ[n][r], kv = aK[n][r];
      const unsigned short qh = f2bf(qv), kh = f2bf(kv);
      qh_l[off] = qh;
      ql_l[off] = f2bf(qv - bf2f(qh));
      kh_l[off] = kh;
      kl_l[off] = f2bf(kv - bf2f(kh));
    }
  }
  __syncthreads();
  f4 aS[8];
#pragma unroll
  for (int n = 0; n < 8; ++n) aS[n] = zero;
#pragma unroll
  for (int kt = 0; kt < 2; ++kt) {
    const int qoff = qswz(r0 + lr, kt * 32 + lg * 8);
    const bf8 fqh = *(const bf8*)(qh_l + qoff);
    const bf8 fql = *(const bf8*)(ql_l + qoff);
#pragma unroll
    for (int n = 0; n < 8; ++n) {
      const int koff = qswz(n * 16 + lr, kt * 32 + lg * 8);
      const bf8 fkh = *(const bf8*)(kh_l + koff);
      const bf8 fkl = *(const bf8*)(kl_l + koff);
      aS[n] = MFMA16(fqh, fkh, aS[n]);
      aS[n] = MFMA16(fqh, fkl, aS[n]);
      aS[n] = MFMA16(fql, fkh, aS[n]);
    }
  }
  float* __restrict__ Sb = S + (size_t)bt * (Nv * Nv);
#pragma unroll
  for (int n = 0; n < 8; ++n) {
#pragma unroll
    for (int r = 0; r < 4; ++r) {
      Sb[(r0 + 4 * lg + r) * Nv + n * 16 + lr] = aS[n][r] * 0.125f;
    }
  }
}

__global__ __launch_bounds__(512) void av_kernel(
    const float* __restrict__ x, const unsigned short* __restrict__ wvf,
    const float* __restrict__ A, float* __restrict__ out) {
  __shared__ alignas(16) unsigned short vt[P2v * Nv];  // 64 KB
  const int bt = blockIdx.x;
  const float* __restrict__ X = x + (size_t)bt * (Nv * P2v);
  const float* __restrict__ Ab = A + (size_t)bt * (Nv * Nv);
  float* __restrict__ ob = out + (size_t)bt * (Nv * P2v);
  const int tid = threadIdx.x, lane = tid & 63, wid = tid >> 6;
  const int lg = lane >> 4, lr = lane & 15;
  const int r0 = wid * 16;

  const f4 zero = {0.f, 0.f, 0.f, 0.f};
  f4 aV[16];
#pragma unroll
  for (int n = 0; n < 16; ++n) aV[n] = zero;
#pragma unroll 2
  for (int kt = 0; kt < 8; ++kt) {
    const float* xr = X + (r0 + lr) * P2v + kt * 32 + lg * 8;
    const float4 x0 = *(const float4*)(xr);
    const float4 x1 = *(const float4*)(xr + 4);
    const float xs[8] = {x0.x, x0.y, x0.z, x0.w, x1.x, x1.y, x1.z, x1.w};
    B8U xh;
#pragma unroll
    for (int j = 0; j < 8; ++j) xh.s[j] = (short)f2bf(xs[j]);
#pragma unroll
    for (int n = 0; n < 16; ++n) {
      const int o = ((kt * 16 + n) * 64 + lane) * 8;
      const bf8 wv = *(const bf8*)(wvf + o);
      aV[n] = MFMA16(xh.v, wv, aV[n]);
    }
  }
  // packed 8B swizzled V^T writes (j0..j0+3 stay in one granule)
  const int j0 = r0 + 4 * lg;
#pragma unroll
  for (int n = 0; n < 16; ++n) {
    const int q = n * 16 + lr;
    ushort4 pk;
    pk.x = f2bf(aV[n][0]);
    pk.y = f2bf(aV[n][1]);
    pk.z = f2bf(aV[n][2]);
    pk.w = f2bf(aV[n][3]);
    *(ushort4*)(vt + vswz(q, j0)) = pk;
  }
  __syncthreads();

  f4 aO[16];
#pragma unroll
  for (int n = 0; n < 16; ++n) aO[n] = zero;
#pragma unroll
  for (int kt = 0; kt < 4; ++kt) {
    const float* ar = Ab + (r0 + lr) * Nv + kt * 32 + lg * 8;
    const float4 a0 = *(const float4*)(ar);
    const float4 a1 = *(const float4*)(ar + 4);
    const float as_[8] = {a0.x, a0.y, a0.z, a0.w, a1.x, a1.y, a1.z, a1.w};
    B8U af;
#pragma unroll
    for (int j = 0; j < 8; ++j) af.s[j] = (short)f2bf(as_[j]);
#pragma unroll
    for (int n = 0; n < 16; ++n) {
      const int voff = vswz(n * 16 + lr, kt * 32 + lg * 8);
      const bf8 vf = *(const bf8*)(vt + voff);
      aO[n] = MFMA16(af.v, vf, aO[n]);
    }
  }
#pragma unroll
  for (int n = 0; n < 16; ++n) {
#pragma unroll
    for (int r = 0; r < 4; ++r) {
      ob[(r0 + 4 * lg + r) * P2v + n * 16 + lr] = aO[n][r];
    }
  }
}

extern "C" void kernel_launch(void* const* d_in, const int* in_sizes, int n_in,
                              void* d_out, int out_size, void* d_ws,
                              size_t ws_size, hipStream_t stream) {
  const float* x = (const float*)d_in[0];
  const float* Wq = (const float*)d_in[1];
  const float* Wk = (const float*)d_in[2];
  const float* Wv = (const float*)d_in[3];
  float* out = (float*)d_out;

  // ws layout: W fragments (256 KB) | S fp32 (33.55 MB) | Vt bf16 (33.55 MB)
  unsigned short* wqh = (unsigned short*)d_ws;
  unsigned short* wql = wqh + 16384;
  unsigned short* wkh = wql + 16384;
  unsigned short* wkl = wkh + 16384;
  unsigned short* wvf = wkl + 16384;  // 65536 elems
  float* S = (float*)((char*)d_ws + 262144);
  unsigned short* Vt = (unsigned short*)((char*)d_ws + 262144 + 33554432);
  const size_t need_big = 262144ull + 33554432ull + 33554432ull;

  hipLaunchKernelGGL(prep_w_kernel, dim3(384), dim3(256), 0, stream, Wq, Wk,
                     Wv, wqh, wql, wkh, wkl, wvf);
  if (ws_size >= need_big) {
    hipLaunchKernelGGL(qkv_kernel, dim3(Bv * Tv), dim3(512), 0, stream, x, wqh,
                       wql, wkh, wkl, wvf, S, Vt);
    hipLaunchKernelGGL(softmax_t_kernel, dim3(Bv * Nv * Nv / 256), dim3(256),
                       0, stream, S);
    hipLaunchKernelGGL(av_stage_kernel, dim3(Bv * Tv), dim3(512), 0, stream, S,
                       Vt, out);
  } else {
    hipLaunchKernelGGL(qk_kernel, dim3(Bv * Tv), dim3(512), 0, stream, x, wqh,
                       wql, wkh, wkl, S);
    hipLaunchKernelGGL(softmax_t_kernel, dim3(Bv * Nv * Nv / 256), dim3(256),
                       0, stream, S);
    hipLaunchKernelGGL(av_kernel, dim3(Bv * Tv), dim3(512), 0, stream, x, wvf,
                       S, out);
  }
}

// Round 5
// 86.345 us; speedup vs baseline: 1.6787x; 1.6787x over previous
//
#include <hip/hip_runtime.h>
#include <hip/hip_bf16.h>

#define Bv 8
#define Tv 64
#define Nv 128
#define P2v 256
#define KSv 64

typedef __attribute__((ext_vector_type(8))) short bf8;   // 8 bf16 in 4 VGPRs
typedef __attribute__((ext_vector_type(4))) float f4;    // MFMA C/D frag

#define MFMA16(a, b, c) __builtin_amdgcn_mfma_f32_16x16x32_bf16((a), (b), (c), 0, 0, 0)

__device__ __forceinline__ unsigned short f2bf(float f) {
  unsigned u = __float_as_uint(f);
  return (unsigned short)((u + 0x7fffu + ((u >> 16) & 1u)) >> 16);
}
__device__ __forceinline__ float bf2f(unsigned short h) {
  return __uint_as_float(((unsigned)h) << 16);
}

// [R][64] bf16, XOR-swizzled 16B granules
__device__ __forceinline__ int swz64(int r, int c) {
  return r * 64 + ((((c >> 3)) ^ (r & 7)) << 3) + (c & 7);
}
// [R][128] bf16, XOR-swizzled
__device__ __forceinline__ int swz128(int r, int c) {
  return r * 128 + ((((c >> 3)) ^ (r & 7)) << 3) + (c & 7);
}

// ---------------------------------------------------------------------------
// Prep: W_Q, W_K -> split hi/lo bf16 fragment-linear; W_V -> bf16 frag-linear.
// Fragment order: [kt][n][lane][jj], elem = W[kt*32 + 8*(lane>>4)+jj][n*16+(lane&15)]
// ---------------------------------------------------------------------------
__global__ __launch_bounds__(256) void prep_w_kernel(
    const float* __restrict__ Wq, const float* __restrict__ Wk,
    const float* __restrict__ Wv, unsigned short* __restrict__ wqh,
    unsigned short* __restrict__ wql, unsigned short* __restrict__ wkh,
    unsigned short* __restrict__ wkl, unsigned short* __restrict__ wvf) {
  const int e = blockIdx.x * 256 + threadIdx.x;  // 0..98303
  if (e < 32768) {
    const float* W = (e < 16384) ? Wq : Wk;
    unsigned short* oh = (e < 16384) ? wqh : wkh;
    unsigned short* ol = (e < 16384) ? wql : wkl;
    const int t = e & 16383;
    const int jj = t & 7, lane = (t >> 3) & 63, nt = (t >> 9) & 3, pt = t >> 11;
    const int p = pt * 32 + 8 * (lane >> 4) + jj;
    const int n = nt * 16 + (lane & 15);
    const float v = W[p * KSv + n];
    const unsigned short h = f2bf(v);
    oh[t] = h;
    ol[t] = f2bf(v - bf2f(h));
  } else {
    const int t = e - 32768;  // 0..65535
    const int jj = t & 7, lane = (t >> 3) & 63, nt = (t >> 9) & 15, pt = t >> 13;
    const int p = pt * 32 + 8 * (lane >> 4) + jj;
    const int q = nt * 16 + (lane & 15);
    wvf[t] = f2bf(Wv[p * P2v + q]);
  }
}

// ---------------------------------------------------------------------------
// Kernel A: per (b,t). Phase 1 (n-specialized): waves 0-3 compute Q n-tiles,
// waves 4-7 K n-tiles; X staged hi/lo in a DEDICATED LDS buffer (no aliasing).
// Phase 2 (row-specialized): S = Q K^T / 8 (bf16x3) -> ws fp32.
// LDS: 6 separate arrays, 96 KB total, single-writer per element.
// ---------------------------------------------------------------------------
__global__ __launch_bounds__(512) void qk_kernel(
    const float* __restrict__ x, const unsigned short* __restrict__ wqh,
    const unsigned short* __restrict__ wql,
    const unsigned short* __restrict__ wkh,
    const unsigned short* __restrict__ wkl, float* __restrict__ S) {
  __shared__ alignas(16) unsigned short xh_l[Nv * KSv];  // 16 KB stage hi
  __shared__ alignas(16) unsigned short xl_l[Nv * KSv];  // 16 KB stage lo
  __shared__ alignas(16) unsigned short qh_l[Nv * KSv];  // 16 KB Q hi
  __shared__ alignas(16) unsigned short ql_l[Nv * KSv];  // 16 KB Q lo
  __shared__ alignas(16) unsigned short kh_l[Nv * KSv];  // 16 KB K hi
  __shared__ alignas(16) unsigned short kl_l[Nv * KSv];  // 16 KB K lo
  const int bt = blockIdx.x;
  const float* __restrict__ X = x + (size_t)bt * (Nv * P2v);
  const int tid = threadIdx.x, lane = tid & 63, wid = tid >> 6;
  const int lg = lane >> 4, lr = lane & 15;
  const bool isQ = (wid < 4);
  const int nt = wid & 3;
  const unsigned short* __restrict__ wh = isQ ? wqh : wkh;
  const unsigned short* __restrict__ wl = isQ ? wql : wkl;

  const f4 zero = {0.f, 0.f, 0.f, 0.f};
  f4 acc[8];
#pragma unroll
  for (int rt = 0; rt < 8; ++rt) acc[rt] = zero;

  const int srow = tid >> 4;      // 0..31
  const int sp = (tid & 15) * 4;  // 0,4,..,60

  for (int c = 0; c < 4; ++c) {
    __syncthreads();  // previous chunk's reads complete before overwrite
#pragma unroll
    for (int pass = 0; pass < 4; ++pass) {
      const int row = srow + pass * 32;
      const float4 v = *(const float4*)(X + row * P2v + c * 64 + sp);
      ushort4 h, l;
      h.x = f2bf(v.x); l.x = f2bf(v.x - bf2f(h.x));
      h.y = f2bf(v.y); l.y = f2bf(v.y - bf2f(h.y));
      h.z = f2bf(v.z); l.z = f2bf(v.z - bf2f(h.z));
      h.w = f2bf(v.w); l.w = f2bf(v.w - bf2f(h.w));
      const int off = swz64(row, sp);
      *(ushort4*)(xh_l + off) = h;
      *(ushort4*)(xl_l + off) = l;
    }
    __syncthreads();
#pragma unroll
    for (int ktl = 0; ktl < 2; ++ktl) {
      const int kt = c * 2 + ktl;
      const int o = ((kt * 4 + nt) * 64 + lane) * 8;
      const bf8 fh = *(const bf8*)(wh + o);
      const bf8 fl = *(const bf8*)(wl + o);
#pragma unroll
      for (int rt = 0; rt < 8; ++rt) {
        const int xoff = swz64(rt * 16 + lr, ktl * 32 + lg * 8);
        const bf8 xh = *(const bf8*)(xh_l + xoff);
        const bf8 xl = *(const bf8*)(xl_l + xoff);
        acc[rt] = MFMA16(xh, fh, acc[rt]);
        acc[rt] = MFMA16(xh, fl, acc[rt]);
        acc[rt] = MFMA16(xl, fh, acc[rt]);
      }
    }
  }

  // Split writes go to DISJOINT arrays (q*/k*), safe while other waves still
  // read the stage arrays — no barrier needed here.
  unsigned short* const oh = isQ ? qh_l : kh_l;
  unsigned short* const ol = isQ ? ql_l : kl_l;
#pragma unroll
  for (int rt = 0; rt < 8; ++rt) {
#pragma unroll
    for (int rr = 0; rr < 4; ++rr) {
      const int i = rt * 16 + 4 * lg + rr;
      const int ks = nt * 16 + lr;
      const int off = swz64(i, ks);
      const float v = acc[rt][rr];
      const unsigned short h = f2bf(v);
      oh[off] = h;
      ol[off] = f2bf(v - bf2f(h));
    }
  }
  __syncthreads();

  // Phase 2: S = Q K^T / 8 (row-specialized, bf16x3)
  const int r0 = wid * 16;
  f4 aS[8];
#pragma unroll
  for (int n = 0; n < 8; ++n) aS[n] = zero;
#pragma unroll
  for (int kt2 = 0; kt2 < 2; ++kt2) {
    const int qoff = swz64(r0 + lr, kt2 * 32 + lg * 8);
    const bf8 fqh = *(const bf8*)(qh_l + qoff);
    const bf8 fql = *(const bf8*)(ql_l + qoff);
#pragma unroll
    for (int n = 0; n < 8; ++n) {
      const int koff = swz64(n * 16 + lr, kt2 * 32 + lg * 8);
      const bf8 fkh = *(const bf8*)(kh_l + koff);
      const bf8 fkl = *(const bf8*)(kl_l + koff);
      aS[n] = MFMA16(fqh, fkh, aS[n]);
      aS[n] = MFMA16(fqh, fkl, aS[n]);
      aS[n] = MFMA16(fql, fkh, aS[n]);
    }
  }
  float* __restrict__ Sb = S + (size_t)bt * (Nv * Nv);
#pragma unroll
  for (int n = 0; n < 8; ++n) {
#pragma unroll
    for (int rr = 0; rr < 4; ++rr) {
      Sb[(r0 + 4 * lg + rr) * Nv + n * 16 + lr] = aS[n][rr] * 0.125f;
    }
  }
}

// ---------------------------------------------------------------------------
// Kernel B: softmax over T axis; read fp32 S, write bf16 A.
// ---------------------------------------------------------------------------
__global__ __launch_bounds__(256) void softmax_t_kernel(
    const float* __restrict__ S, unsigned short* __restrict__ Abf) {
  const int idx = blockIdx.x * 256 + threadIdx.x;  // 0 .. B*N*N-1
  const int j = idx & (Nv - 1);
  const int i = (idx >> 7) & (Nv - 1);
  const int b = idx >> 14;
  const size_t base = ((size_t)b * Tv * Nv * Nv) + (size_t)i * Nv + j;

  float vals[Tv];
  float m = -1e30f;
#pragma unroll
  for (int t = 0; t < Tv; ++t) {
    const float v = S[base + (size_t)t * Nv * Nv];
    vals[t] = v;
    m = fmaxf(m, v);
  }
  float s = 0.f;
#pragma unroll
  for (int t = 0; t < Tv; ++t) {
    const float e = __expf(vals[t] - m);
    vals[t] = e;
    s += e;
  }
  const float inv = 1.f / s;
#pragma unroll
  for (int t = 0; t < Tv; ++t) {
    Abf[base + (size_t)t * Nv * Nv] = f2bf(vals[t] * inv);
  }
}

// ---------------------------------------------------------------------------
// Kernel C: per (b,t). Phase 1 (n-specialized, ntile = h*8 + wid): V = X@Wv
// with X-hi staged in a dedicated 16 KB buffer. V^T consumed in two
// 128-column halves through a 32 KB buffer (48 KB LDS total, no aliasing).
// Phase 2: out = A(bf16) @ V.
// ---------------------------------------------------------------------------
__global__ __launch_bounds__(512) void av_kernel(
    const float* __restrict__ x, const unsigned short* __restrict__ wvf,
    const unsigned short* __restrict__ Abf, float* __restrict__ out) {
  __shared__ alignas(16) unsigned short xa[Nv * KSv];    // 16 KB X-hi stage
  __shared__ alignas(16) unsigned short vth[Nv * Nv];    // 32 KB V^T half
  const int bt = blockIdx.x;
  const float* __restrict__ X = x + (size_t)bt * (Nv * P2v);
  const unsigned short* __restrict__ Ab = Abf + (size_t)bt * (Nv * Nv);
  float* __restrict__ ob = out + (size_t)bt * (Nv * P2v);
  const int tid = threadIdx.x, lane = tid & 63, wid = tid >> 6;
  const int lg = lane >> 4, lr = lane & 15;
  const int r0 = wid * 16;

  // Preload A fragments (bf16, 4 x 16B per lane) — reused by both halves.
  bf8 af[4];
#pragma unroll
  for (int kt = 0; kt < 4; ++kt) {
    af[kt] = *(const bf8*)(Ab + (r0 + lr) * Nv + kt * 32 + lg * 8);
  }

  const f4 zero = {0.f, 0.f, 0.f, 0.f};
  f4 aV[16];  // [h*8 + rt] : ntile = h*8 + wid
#pragma unroll
  for (int n = 0; n < 16; ++n) aV[n] = zero;

  const int srow = tid >> 4;
  const int sp = (tid & 15) * 4;

  for (int c = 0; c < 4; ++c) {
    __syncthreads();
#pragma unroll
    for (int pass = 0; pass < 4; ++pass) {
      const int row = srow + pass * 32;
      const float4 v = *(const float4*)(X + row * P2v + c * 64 + sp);
      ushort4 h;
      h.x = f2bf(v.x);
      h.y = f2bf(v.y);
      h.z = f2bf(v.z);
      h.w = f2bf(v.w);
      *(ushort4*)(xa + swz64(row, sp)) = h;
    }
    __syncthreads();
#pragma unroll
    for (int ktl = 0; ktl < 2; ++ktl) {
      const int kt = c * 2 + ktl;
#pragma unroll
      for (int h = 0; h < 2; ++h) {
        const int ntile = h * 8 + wid;
        const int o = ((kt * 16 + ntile) * 64 + lane) * 8;
        const bf8 fv = *(const bf8*)(wvf + o);
#pragma unroll
        for (int rt = 0; rt < 8; ++rt) {
          const bf8 xh =
              *(const bf8*)(xa + swz64(rt * 16 + lr, ktl * 32 + lg * 8));
          aV[h * 8 + rt] = MFMA16(xh, fv, aV[h * 8 + rt]);
        }
      }
    }
  }

  // Two halves: write V^T half (local rows 0..127), sync, A@V, out cols half.
#pragma unroll
  for (int h = 0; h < 2; ++h) {
    if (h == 1) __syncthreads();  // half-0 reads done before overwrite
    // wave's ntile = h*8+wid -> global q = h*128 + wid*16 + lr; local row:
    const int ql = wid * 16 + lr;
#pragma unroll
    for (int rt = 0; rt < 8; ++rt) {
      const int j0 = rt * 16 + 4 * lg;
      ushort4 pk;
      pk.x = f2bf(aV[h * 8 + rt][0]);
      pk.y = f2bf(aV[h * 8 + rt][1]);
      pk.z = f2bf(aV[h * 8 + rt][2]);
      pk.w = f2bf(aV[h * 8 + rt][3]);
      *(ushort4*)(vth + swz128(ql, j0)) = pk;
    }
    __syncthreads();

    f4 aO[8];
#pragma unroll
    for (int n = 0; n < 8; ++n) aO[n] = zero;
#pragma unroll
    for (int kt = 0; kt < 4; ++kt) {
#pragma unroll
      for (int n = 0; n < 8; ++n) {
        const bf8 vf =
            *(const bf8*)(vth + swz128(n * 16 + lr, kt * 32 + lg * 8));
        aO[n] = MFMA16(af[kt], vf, aO[n]);
      }
    }
#pragma unroll
    for (int n = 0; n < 8; ++n) {
#pragma unroll
      for (int rr = 0; rr < 4; ++rr) {
        ob[(r0 + 4 * lg + rr) * P2v + h * 128 + n * 16 + lr] = aO[n][rr];
      }
    }
  }
}

extern "C" void kernel_launch(void* const* d_in, const int* in_sizes, int n_in,
                              void* d_out, int out_size, void* d_ws,
                              size_t ws_size, hipStream_t stream) {
  const float* x = (const float*)d_in[0];
  const float* Wq = (const float*)d_in[1];
  const float* Wk = (const float*)d_in[2];
  const float* Wv = (const float*)d_in[3];
  float* out = (float*)d_out;

  // ws: W frags (256 KB) | S fp32 (33.55 MB) | A bf16 (16.78 MB) = 50.6 MB
  // (round 3 ran a 67.4 MB layout successfully, so ws_size is sufficient)
  unsigned short* wqh = (unsigned short*)d_ws;
  unsigned short* wql = wqh + 16384;
  unsigned short* wkh = wql + 16384;
  unsigned short* wkl = wkh + 16384;
  unsigned short* wvf = wkl + 16384;  // 65536 elems
  float* S = (float*)((char*)d_ws + 262144);
  unsigned short* Abf = (unsigned short*)((char*)d_ws + 262144 + 33554432);

  hipLaunchKernelGGL(prep_w_kernel, dim3(384), dim3(256), 0, stream, Wq, Wk,
                     Wv, wqh, wql, wkh, wkl, wvf);
  hipLaunchKernelGGL(qk_kernel, dim3(Bv * Tv), dim3(512), 0, stream, x, wqh,
                     wql, wkh, wkl, S);
  hipLaunchKernelGGL(softmax_t_kernel, dim3(Bv * Nv * Nv / 256), dim3(256), 0,
                     stream, S, Abf);
  hipLaunchKernelGGL(av_kernel, dim3(Bv * Tv), dim3(512), 0, stream, x, wvf,
                     Abf, out);
}

// Round 6
// 81.486 us; speedup vs baseline: 1.7788x; 1.0596x over previous
//
#include <hip/hip_runtime.h>
#include <hip/hip_bf16.h>

#define Bv 8
#define Tv 64
#define Nv 128
#define P2v 256
#define KSv 64

typedef __attribute__((ext_vector_type(8))) short bf8;   // 8 bf16 in 4 VGPRs
typedef __attribute__((ext_vector_type(4))) float f4;    // MFMA C/D frag

#define MFMA16(a, b, c) __builtin_amdgcn_mfma_f32_16x16x32_bf16((a), (b), (c), 0, 0, 0)

__device__ __forceinline__ unsigned short f2bf(float f) {
  unsigned u = __float_as_uint(f);
  return (unsigned short)((u + 0x7fffu + ((u >> 16) & 1u)) >> 16);
}
__device__ __forceinline__ float bf2f(unsigned short h) {
  return __uint_as_float(((unsigned)h) << 16);
}

// [R][64] bf16, XOR-swizzled 16B granules
__device__ __forceinline__ int swz64(int r, int c) {
  return r * 64 + ((((c >> 3)) ^ (r & 7)) << 3) + (c & 7);
}
// [R][32] bf16, XOR-swizzled 16B granules (4 granules/row, xor with row&3)
__device__ __forceinline__ int swz32(int r, int c) {
  return r * 32 + ((((c >> 3)) ^ (r & 3)) << 3) + (c & 7);
}
// [R][128] bf16, XOR-swizzled
__device__ __forceinline__ int swz128(int r, int c) {
  return r * 128 + ((((c >> 3)) ^ (r & 7)) << 3) + (c & 7);
}

// ---------------------------------------------------------------------------
// Prep: W_Q, W_K -> split hi/lo bf16 fragment-linear; W_V -> bf16 frag-linear.
// Fragment order: [kt][n][lane][jj], elem = W[kt*32 + 8*(lane>>4)+jj][n*16+(lane&15)]
// ---------------------------------------------------------------------------
__global__ __launch_bounds__(256) void prep_w_kernel(
    const float* __restrict__ Wq, const float* __restrict__ Wk,
    const float* __restrict__ Wv, unsigned short* __restrict__ wqh,
    unsigned short* __restrict__ wql, unsigned short* __restrict__ wkh,
    unsigned short* __restrict__ wkl, unsigned short* __restrict__ wvf) {
  const int e = blockIdx.x * 256 + threadIdx.x;  // 0..98303
  if (e < 32768) {
    const float* W = (e < 16384) ? Wq : Wk;
    unsigned short* oh = (e < 16384) ? wqh : wkh;
    unsigned short* ol = (e < 16384) ? wql : wkl;
    const int t = e & 16383;
    const int jj = t & 7, lane = (t >> 3) & 63, nt = (t >> 9) & 3, pt = t >> 11;
    const int p = pt * 32 + 8 * (lane >> 4) + jj;
    const int n = nt * 16 + (lane & 15);
    const float v = W[p * KSv + n];
    const unsigned short h = f2bf(v);
    oh[t] = h;
    ol[t] = f2bf(v - bf2f(h));
  } else {
    const int t = e - 32768;  // 0..65535
    const int jj = t & 7, lane = (t >> 3) & 63, nt = (t >> 9) & 15, pt = t >> 13;
    const int p = pt * 32 + 8 * (lane >> 4) + jj;
    const int q = nt * 16 + (lane & 15);
    wvf[t] = f2bf(Wv[p * P2v + q]);
  }
}

// ---------------------------------------------------------------------------
// Kernel A: per (b,t). Phase 1 (n-specialized): waves 0-3 compute Q n-tiles,
// waves 4-7 K n-tiles; X staged hi/lo in 32-column chunks (16 KB).
// Phase 2 (row-specialized): S = Q K^T / 8 (bf16x3) -> ws fp32.
// LDS: 80 KB total -> 2 blocks/CU (160 KB), single-writer per element.
// ---------------------------------------------------------------------------
__global__ __launch_bounds__(512) void qk_kernel(
    const float* __restrict__ x, const unsigned short* __restrict__ wqh,
    const unsigned short* __restrict__ wql,
    const unsigned short* __restrict__ wkh,
    const unsigned short* __restrict__ wkl, float* __restrict__ S) {
  __shared__ alignas(16) unsigned short xh_l[Nv * 32];   // 8 KB stage hi
  __shared__ alignas(16) unsigned short xl_l[Nv * 32];   // 8 KB stage lo
  __shared__ alignas(16) unsigned short qh_l[Nv * KSv];  // 16 KB Q hi
  __shared__ alignas(16) unsigned short ql_l[Nv * KSv];  // 16 KB Q lo
  __shared__ alignas(16) unsigned short kh_l[Nv * KSv];  // 16 KB K hi
  __shared__ alignas(16) unsigned short kl_l[Nv * KSv];  // 16 KB K lo
  const int bt = blockIdx.x;
  const float* __restrict__ X = x + (size_t)bt * (Nv * P2v);
  const int tid = threadIdx.x, lane = tid & 63, wid = tid >> 6;
  const int lg = lane >> 4, lr = lane & 15;
  const bool isQ = (wid < 4);
  const int nt = wid & 3;
  const unsigned short* __restrict__ wh = isQ ? wqh : wkh;
  const unsigned short* __restrict__ wl = isQ ? wql : wkl;

  const f4 zero = {0.f, 0.f, 0.f, 0.f};
  f4 acc[8];
#pragma unroll
  for (int rt = 0; rt < 8; ++rt) acc[rt] = zero;

  const int srow = tid >> 2;      // 0..127 (one row per 4 threads)
  const int sp = (tid & 3) * 8;   // 0,8,16,24

  for (int c = 0; c < 8; ++c) {   // 32-col chunks; chunk c == kt c
    __syncthreads();  // previous chunk's reads complete before overwrite
    {
      const float4 v0 = *(const float4*)(X + srow * P2v + c * 32 + sp);
      const float4 v1 = *(const float4*)(X + srow * P2v + c * 32 + sp + 4);
      ushort4 h0, l0, h1, l1;
      h0.x = f2bf(v0.x); l0.x = f2bf(v0.x - bf2f(h0.x));
      h0.y = f2bf(v0.y); l0.y = f2bf(v0.y - bf2f(h0.y));
      h0.z = f2bf(v0.z); l0.z = f2bf(v0.z - bf2f(h0.z));
      h0.w = f2bf(v0.w); l0.w = f2bf(v0.w - bf2f(h0.w));
      h1.x = f2bf(v1.x); l1.x = f2bf(v1.x - bf2f(h1.x));
      h1.y = f2bf(v1.y); l1.y = f2bf(v1.y - bf2f(h1.y));
      h1.z = f2bf(v1.z); l1.z = f2bf(v1.z - bf2f(h1.z));
      h1.w = f2bf(v1.w); l1.w = f2bf(v1.w - bf2f(h1.w));
      // sp..sp+7 is one 16B granule -> single write per array
      const int off = swz32(srow, sp);
      *(ushort4*)(xh_l + off) = h0;
      *(ushort4*)(xh_l + off + 4) = h1;
      *(ushort4*)(xl_l + off) = l0;
      *(ushort4*)(xl_l + off + 4) = l1;
    }
    __syncthreads();
    {
      const int o = ((c * 4 + nt) * 64 + lane) * 8;
      const bf8 fh = *(const bf8*)(wh + o);
      const bf8 fl = *(const bf8*)(wl + o);
#pragma unroll
      for (int rt = 0; rt < 8; ++rt) {
        const int xoff = swz32(rt * 16 + lr, lg * 8);
        const bf8 xh = *(const bf8*)(xh_l + xoff);
        const bf8 xl = *(const bf8*)(xl_l + xoff);
        acc[rt] = MFMA16(xh, fh, acc[rt]);
        acc[rt] = MFMA16(xh, fl, acc[rt]);
        acc[rt] = MFMA16(xl, fh, acc[rt]);
      }
    }
  }

  // Split writes go to DISJOINT arrays (q*/k*), safe while other waves still
  // read the stage arrays — no barrier needed here.
  unsigned short* const oh = isQ ? qh_l : kh_l;
  unsigned short* const ol = isQ ? ql_l : kl_l;
#pragma unroll
  for (int rt = 0; rt < 8; ++rt) {
#pragma unroll
    for (int rr = 0; rr < 4; ++rr) {
      const int i = rt * 16 + 4 * lg + rr;
      const int ks = nt * 16 + lr;
      const int off = swz64(i, ks);
      const float v = acc[rt][rr];
      const unsigned short h = f2bf(v);
      oh[off] = h;
      ol[off] = f2bf(v - bf2f(h));
    }
  }
  __syncthreads();

  // Phase 2: S = Q K^T / 8 (row-specialized, bf16x3)
  const int r0 = wid * 16;
  f4 aS[8];
#pragma unroll
  for (int n = 0; n < 8; ++n) aS[n] = zero;
#pragma unroll
  for (int kt2 = 0; kt2 < 2; ++kt2) {
    const int qoff = swz64(r0 + lr, kt2 * 32 + lg * 8);
    const bf8 fqh = *(const bf8*)(qh_l + qoff);
    const bf8 fql = *(const bf8*)(ql_l + qoff);
#pragma unroll
    for (int n = 0; n < 8; ++n) {
      const int koff = swz64(n * 16 + lr, kt2 * 32 + lg * 8);
      const bf8 fkh = *(const bf8*)(kh_l + koff);
      const bf8 fkl = *(const bf8*)(kl_l + koff);
      aS[n] = MFMA16(fqh, fkh, aS[n]);
      aS[n] = MFMA16(fqh, fkl, aS[n]);
      aS[n] = MFMA16(fql, fkh, aS[n]);
    }
  }
  float* __restrict__ Sb = S + (size_t)bt * (Nv * Nv);
#pragma unroll
  for (int n = 0; n < 8; ++n) {
#pragma unroll
    for (int rr = 0; rr < 4; ++rr) {
      Sb[(r0 + 4 * lg + rr) * Nv + n * 16 + lr] = aS[n][rr] * 0.125f;
    }
  }
}

// ---------------------------------------------------------------------------
// Kernel B: softmax over T axis; read fp32 S, write bf16 A.
// ---------------------------------------------------------------------------
__global__ __launch_bounds__(256) void softmax_t_kernel(
    const float* __restrict__ S, unsigned short* __restrict__ Abf) {
  const int idx = blockIdx.x * 256 + threadIdx.x;  // 0 .. B*N*N-1
  const int j = idx & (Nv - 1);
  const int i = (idx >> 7) & (Nv - 1);
  const int b = idx >> 14;
  const size_t base = ((size_t)b * Tv * Nv * Nv) + (size_t)i * Nv + j;

  float vals[Tv];
  float m = -1e30f;
#pragma unroll
  for (int t = 0; t < Tv; ++t) {
    const float v = S[base + (size_t)t * Nv * Nv];
    vals[t] = v;
    m = fmaxf(m, v);
  }
  float s = 0.f;
#pragma unroll
  for (int t = 0; t < Tv; ++t) {
    const float e = __expf(vals[t] - m);
    vals[t] = e;
    s += e;
  }
  const float inv = 1.f / s;
#pragma unroll
  for (int t = 0; t < Tv; ++t) {
    Abf[base + (size_t)t * Nv * Nv] = f2bf(vals[t] * inv);
  }
}

// ---------------------------------------------------------------------------
// Kernel C: per (b,t). Phase 1 (n-specialized, ntile = h*8 + wid): V = X@Wv
// with X-hi staged in a dedicated 16 KB buffer. V^T consumed in two
// 128-column halves through a 32 KB buffer (48 KB LDS total, no aliasing).
// Phase 2: out = A(bf16) @ V.
// ---------------------------------------------------------------------------
__global__ __launch_bounds__(512) void av_kernel(
    const float* __restrict__ x, const unsigned short* __restrict__ wvf,
    const unsigned short* __restrict__ Abf, float* __restrict__ out) {
  __shared__ alignas(16) unsigned short xa[Nv * KSv];    // 16 KB X-hi stage
  __shared__ alignas(16) unsigned short vth[Nv * Nv];    // 32 KB V^T half
  const int bt = blockIdx.x;
  const float* __restrict__ X = x + (size_t)bt * (Nv * P2v);
  const unsigned short* __restrict__ Ab = Abf + (size_t)bt * (Nv * Nv);
  float* __restrict__ ob = out + (size_t)bt * (Nv * P2v);
  const int tid = threadIdx.x, lane = tid & 63, wid = tid >> 6;
  const int lg = lane >> 4, lr = lane & 15;
  const int r0 = wid * 16;

  // Preload A fragments (bf16, 4 x 16B per lane) — reused by both halves.
  bf8 af[4];
#pragma unroll
  for (int kt = 0; kt < 4; ++kt) {
    af[kt] = *(const bf8*)(Ab + (r0 + lr) * Nv + kt * 32 + lg * 8);
  }

  const f4 zero = {0.f, 0.f, 0.f, 0.f};
  f4 aV[16];  // [h*8 + rt] : ntile = h*8 + wid
#pragma unroll
  for (int n = 0; n < 16; ++n) aV[n] = zero;

  const int srow = tid >> 4;
  const int sp = (tid & 15) * 4;

  for (int c = 0; c < 4; ++c) {
    __syncthreads();
#pragma unroll
    for (int pass = 0; pass < 4; ++pass) {
      const int row = srow + pass * 32;
      const float4 v = *(const float4*)(X + row * P2v + c * 64 + sp);
      ushort4 h;
      h.x = f2bf(v.x);
      h.y = f2bf(v.y);
      h.z = f2bf(v.z);
      h.w = f2bf(v.w);
      *(ushort4*)(xa + swz64(row, sp)) = h;
    }
    __syncthreads();
#pragma unroll
    for (int ktl = 0; ktl < 2; ++ktl) {
      const int kt = c * 2 + ktl;
#pragma unroll
      for (int h = 0; h < 2; ++h) {
        const int ntile = h * 8 + wid;
        const int o = ((kt * 16 + ntile) * 64 + lane) * 8;
        const bf8 fv = *(const bf8*)(wvf + o);
#pragma unroll
        for (int rt = 0; rt < 8; ++rt) {
          const bf8 xh =
              *(const bf8*)(xa + swz64(rt * 16 + lr, ktl * 32 + lg * 8));
          aV[h * 8 + rt] = MFMA16(xh, fv, aV[h * 8 + rt]);
        }
      }
    }
  }

  // Two halves: write V^T half (local rows 0..127), sync, A@V, out cols half.
#pragma unroll
  for (int h = 0; h < 2; ++h) {
    if (h == 1) __syncthreads();  // half-0 reads done before overwrite
    // wave's ntile = h*8+wid -> global q = h*128 + wid*16 + lr; local row:
    const int ql = wid * 16 + lr;
#pragma unroll
    for (int rt = 0; rt < 8; ++rt) {
      const int j0 = rt * 16 + 4 * lg;
      ushort4 pk;
      pk.x = f2bf(aV[h * 8 + rt][0]);
      pk.y = f2bf(aV[h * 8 + rt][1]);
      pk.z = f2bf(aV[h * 8 + rt][2]);
      pk.w = f2bf(aV[h * 8 + rt][3]);
      *(ushort4*)(vth + swz128(ql, j0)) = pk;
    }
    __syncthreads();

    f4 aO[8];
#pragma unroll
    for (int n = 0; n < 8; ++n) aO[n] = zero;
#pragma unroll
    for (int kt = 0; kt < 4; ++kt) {
#pragma unroll
      for (int n = 0; n < 8; ++n) {
        const bf8 vf =
            *(const bf8*)(vth + swz128(n * 16 + lr, kt * 32 + lg * 8));
        aO[n] = MFMA16(af[kt], vf, aO[n]);
      }
    }
#pragma unroll
    for (int n = 0; n < 8; ++n) {
#pragma unroll
      for (int rr = 0; rr < 4; ++rr) {
        ob[(r0 + 4 * lg + rr) * P2v + h * 128 + n * 16 + lr] = aO[n][rr];
      }
    }
  }
}

extern "C" void kernel_launch(void* const* d_in, const int* in_sizes, int n_in,
                              void* d_out, int out_size, void* d_ws,
                              size_t ws_size, hipStream_t stream) {
  const float* x = (const float*)d_in[0];
  const float* Wq = (const float*)d_in[1];
  const float* Wk = (const float*)d_in[2];
  const float* Wv = (const float*)d_in[3];
  float* out = (float*)d_out;

  // ws: W frags (256 KB) | S fp32 (33.55 MB) | A bf16 (16.78 MB) = 50.6 MB
  unsigned short* wqh = (unsigned short*)d_ws;
  unsigned short* wql = wqh + 16384;
  unsigned short* wkh = wql + 16384;
  unsigned short* wkl = wkh + 16384;
  unsigned short* wvf = wkl + 16384;  // 65536 elems
  float* S = (float*)((char*)d_ws + 262144);
  unsigned short* Abf = (unsigned short*)((char*)d_ws + 262144 + 33554432);

  hipLaunchKernelGGL(prep_w_kernel, dim3(384), dim3(256), 0, stream, Wq, Wk,
                     Wv, wqh, wql, wkh, wkl, wvf);
  hipLaunchKernelGGL(qk_kernel, dim3(Bv * Tv), dim3(512), 0, stream, x, wqh,
                     wql, wkh, wkl, S);
  hipLaunchKernelGGL(softmax_t_kernel, dim3(Bv * Nv * Nv / 256), dim3(256), 0,
                     stream, S, Abf);
  hipLaunchKernelGGL(av_kernel, dim3(Bv * Tv), dim3(512), 0, stream, x, wvf,
                     Abf, out);
}

// Round 7
// 80.533 us; speedup vs baseline: 1.7999x; 1.0118x over previous
//
#include <hip/hip_runtime.h>
#include <hip/hip_bf16.h>

#define Bv 8
#define Tv 64
#define Nv 128
#define P2v 256
#define KSv 64

typedef __attribute__((ext_vector_type(8))) short bf8;   // 8 bf16 in 4 VGPRs
typedef __attribute__((ext_vector_type(4))) float f4;    // MFMA C/D frag

#define MFMA16(a, b, c) __builtin_amdgcn_mfma_f32_16x16x32_bf16((a), (b), (c), 0, 0, 0)

__device__ __forceinline__ unsigned short f2bf(float f) {
  unsigned u = __float_as_uint(f);
  return (unsigned short)((u + 0x7fffu + ((u >> 16) & 1u)) >> 16);
}
__device__ __forceinline__ float bf2f(unsigned short h) {
  return __uint_as_float(((unsigned)h) << 16);
}

// [R][64] bf16, XOR-swizzled 16B granules
__device__ __forceinline__ int swz64(int r, int c) {
  return r * 64 + ((((c >> 3)) ^ (r & 7)) << 3) + (c & 7);
}
// [R][32] bf16, XOR-swizzled 16B granules (4 granules/row, xor with row&3)
__device__ __forceinline__ int swz32(int r, int c) {
  return r * 32 + ((((c >> 3)) ^ (r & 3)) << 3) + (c & 7);
}
// [R][128] bf16, XOR-swizzled
__device__ __forceinline__ int swz128(int r, int c) {
  return r * 128 + ((((c >> 3)) ^ (r & 7)) << 3) + (c & 7);
}

// ---------------------------------------------------------------------------
// Prep: W_Q, W_K -> split hi/lo bf16 fragment-linear; W_V -> bf16 frag-linear.
// Fragment order: [kt][n][lane][jj], elem = W[kt*32 + 8*(lane>>4)+jj][n*16+(lane&15)]
// ---------------------------------------------------------------------------
__global__ __launch_bounds__(256) void prep_w_kernel(
    const float* __restrict__ Wq, const float* __restrict__ Wk,
    const float* __restrict__ Wv, unsigned short* __restrict__ wqh,
    unsigned short* __restrict__ wql, unsigned short* __restrict__ wkh,
    unsigned short* __restrict__ wkl, unsigned short* __restrict__ wvf) {
  const int e = blockIdx.x * 256 + threadIdx.x;  // 0..98303
  if (e < 32768) {
    const float* W = (e < 16384) ? Wq : Wk;
    unsigned short* oh = (e < 16384) ? wqh : wkh;
    unsigned short* ol = (e < 16384) ? wql : wkl;
    const int t = e & 16383;
    const int jj = t & 7, lane = (t >> 3) & 63, nt = (t >> 9) & 3, pt = t >> 11;
    const int p = pt * 32 + 8 * (lane >> 4) + jj;
    const int n = nt * 16 + (lane & 15);
    const float v = W[p * KSv + n];
    const unsigned short h = f2bf(v);
    oh[t] = h;
    ol[t] = f2bf(v - bf2f(h));
  } else {
    const int t = e - 32768;  // 0..65535
    const int jj = t & 7, lane = (t >> 3) & 63, nt = (t >> 9) & 15, pt = t >> 13;
    const int p = pt * 32 + 8 * (lane >> 4) + jj;
    const int q = nt * 16 + (lane & 15);
    wvf[t] = f2bf(Wv[p * P2v + q]);
  }
}

// ---------------------------------------------------------------------------
// Kernel A: per (b,t). Phase 1 (n-specialized): waves 0-3 Q, waves 4-7 K;
// X staged hi/lo in 32-col chunks (16 KB) with ISSUE-EARLY prefetch of the
// next chunk's X and W-fragment loads (latency hides under MFMA + barrier).
// Phase 2 (row-specialized): S = Q K^T / 8 (bf16x3) -> ws fp32.
// LDS: 80 KB -> 2 blocks/CU.
// ---------------------------------------------------------------------------
__global__ __launch_bounds__(512) void qk_kernel(
    const float* __restrict__ x, const unsigned short* __restrict__ wqh,
    const unsigned short* __restrict__ wql,
    const unsigned short* __restrict__ wkh,
    const unsigned short* __restrict__ wkl, float* __restrict__ S) {
  __shared__ alignas(16) unsigned short xh_l[Nv * 32];   // 8 KB stage hi
  __shared__ alignas(16) unsigned short xl_l[Nv * 32];   // 8 KB stage lo
  __shared__ alignas(16) unsigned short qh_l[Nv * KSv];  // 16 KB Q hi
  __shared__ alignas(16) unsigned short ql_l[Nv * KSv];  // 16 KB Q lo
  __shared__ alignas(16) unsigned short kh_l[Nv * KSv];  // 16 KB K hi
  __shared__ alignas(16) unsigned short kl_l[Nv * KSv];  // 16 KB K lo
  const int bt = blockIdx.x;
  const float* __restrict__ X = x + (size_t)bt * (Nv * P2v);
  const int tid = threadIdx.x, lane = tid & 63, wid = tid >> 6;
  const int lg = lane >> 4, lr = lane & 15;
  const bool isQ = (wid < 4);
  const int nt = wid & 3;
  const unsigned short* __restrict__ wh = isQ ? wqh : wkh;
  const unsigned short* __restrict__ wl = isQ ? wql : wkl;

  const f4 zero = {0.f, 0.f, 0.f, 0.f};
  f4 acc[8];
#pragma unroll
  for (int rt = 0; rt < 8; ++rt) acc[rt] = zero;

  const int srow = tid >> 2;      // 0..127 (one row per 4 threads)
  const int sp = (tid & 3) * 8;   // 0,8,16,24
  const float* __restrict__ Xrow = X + srow * P2v + sp;

  // Prologue: prefetch chunk 0 (X 32B/thread + W frags 32B/lane)
  float4 pv0 = *(const float4*)(Xrow);
  float4 pv1 = *(const float4*)(Xrow + 4);
  bf8 pwh = *(const bf8*)(wh + (nt * 64 + lane) * 8);
  bf8 pwl = *(const bf8*)(wl + (nt * 64 + lane) * 8);

  for (int c = 0; c < 8; ++c) {   // 32-col chunks; chunk c == kt c
    // convert current prefetched X chunk (registers only)
    ushort4 h0, l0, h1, l1;
    h0.x = f2bf(pv0.x); l0.x = f2bf(pv0.x - bf2f(h0.x));
    h0.y = f2bf(pv0.y); l0.y = f2bf(pv0.y - bf2f(h0.y));
    h0.z = f2bf(pv0.z); l0.z = f2bf(pv0.z - bf2f(h0.z));
    h0.w = f2bf(pv0.w); l0.w = f2bf(pv0.w - bf2f(h0.w));
    h1.x = f2bf(pv1.x); l1.x = f2bf(pv1.x - bf2f(h1.x));
    h1.y = f2bf(pv1.y); l1.y = f2bf(pv1.y - bf2f(h1.y));
    h1.z = f2bf(pv1.z); l1.z = f2bf(pv1.z - bf2f(h1.z));
    h1.w = f2bf(pv1.w); l1.w = f2bf(pv1.w - bf2f(h1.w));
    const bf8 cwh = pwh, cwl = pwl;

    __syncthreads();  // previous chunk's LDS reads complete -> buffer free
    const int off = swz32(srow, sp);
    *(ushort4*)(xh_l + off) = h0;
    *(ushort4*)(xh_l + off + 4) = h1;
    *(ushort4*)(xl_l + off) = l0;
    *(ushort4*)(xl_l + off + 4) = l1;

    // issue-early: next chunk's global loads drain across barrier + MFMA
    if (c < 7) {
      pv0 = *(const float4*)(Xrow + (c + 1) * 32);
      pv1 = *(const float4*)(Xrow + (c + 1) * 32 + 4);
      const int wo = (((c + 1) * 4 + nt) * 64 + lane) * 8;
      pwh = *(const bf8*)(wh + wo);
      pwl = *(const bf8*)(wl + wo);
    }
    __syncthreads();
#pragma unroll
    for (int rt = 0; rt < 8; ++rt) {
      const int xoff = swz32(rt * 16 + lr, lg * 8);
      const bf8 xh = *(const bf8*)(xh_l + xoff);
      const bf8 xl = *(const bf8*)(xl_l + xoff);
      acc[rt] = MFMA16(xh, cwh, acc[rt]);
      acc[rt] = MFMA16(xh, cwl, acc[rt]);
      acc[rt] = MFMA16(xl, cwh, acc[rt]);
    }
  }

  // Split writes go to DISJOINT arrays (q*/k*) — no barrier needed here.
  unsigned short* const oh = isQ ? qh_l : kh_l;
  unsigned short* const ol = isQ ? ql_l : kl_l;
#pragma unroll
  for (int rt = 0; rt < 8; ++rt) {
#pragma unroll
    for (int rr = 0; rr < 4; ++rr) {
      const int i = rt * 16 + 4 * lg + rr;
      const int ks = nt * 16 + lr;
      const int off = swz64(i, ks);
      const float v = acc[rt][rr];
      const unsigned short h = f2bf(v);
      oh[off] = h;
      ol[off] = f2bf(v - bf2f(h));
    }
  }
  __syncthreads();

  // Phase 2: S = Q K^T / 8 (row-specialized, bf16x3)
  const int r0 = wid * 16;
  f4 aS[8];
#pragma unroll
  for (int n = 0; n < 8; ++n) aS[n] = zero;
#pragma unroll
  for (int kt2 = 0; kt2 < 2; ++kt2) {
    const int qoff = swz64(r0 + lr, kt2 * 32 + lg * 8);
    const bf8 fqh = *(const bf8*)(qh_l + qoff);
    const bf8 fql = *(const bf8*)(ql_l + qoff);
#pragma unroll
    for (int n = 0; n < 8; ++n) {
      const int koff = swz64(n * 16 + lr, kt2 * 32 + lg * 8);
      const bf8 fkh = *(const bf8*)(kh_l + koff);
      const bf8 fkl = *(const bf8*)(kl_l + koff);
      aS[n] = MFMA16(fqh, fkh, aS[n]);
      aS[n] = MFMA16(fqh, fkl, aS[n]);
      aS[n] = MFMA16(fql, fkh, aS[n]);
    }
  }
  float* __restrict__ Sb = S + (size_t)bt * (Nv * Nv);
#pragma unroll
  for (int n = 0; n < 8; ++n) {
#pragma unroll
    for (int rr = 0; rr < 4; ++rr) {
      Sb[(r0 + 4 * lg + rr) * Nv + n * 16 + lr] = aS[n][rr] * 0.125f;
    }
  }
}

// ---------------------------------------------------------------------------
// Kernel B: softmax over T axis; read fp32 S, write bf16 A.
// ---------------------------------------------------------------------------
__global__ __launch_bounds__(256) void softmax_t_kernel(
    const float* __restrict__ S, unsigned short* __restrict__ Abf) {
  const int idx = blockIdx.x * 256 + threadIdx.x;  // 0 .. B*N*N-1
  const int j = idx & (Nv - 1);
  const int i = (idx >> 7) & (Nv - 1);
  const int b = idx >> 14;
  const size_t base = ((size_t)b * Tv * Nv * Nv) + (size_t)i * Nv + j;

  float vals[Tv];
  float m = -1e30f;
#pragma unroll
  for (int t = 0; t < Tv; ++t) {
    const float v = S[base + (size_t)t * Nv * Nv];
    vals[t] = v;
    m = fmaxf(m, v);
  }
  float s = 0.f;
#pragma unroll
  for (int t = 0; t < Tv; ++t) {
    const float e = __expf(vals[t] - m);
    vals[t] = e;
    s += e;
  }
  const float inv = 1.f / s;
#pragma unroll
  for (int t = 0; t < Tv; ++t) {
    Abf[base + (size_t)t * Nv * Nv] = f2bf(vals[t] * inv);
  }
}

// ---------------------------------------------------------------------------
// Kernel C: per (b,t). Phase 1 (n-specialized, ntile = h*8 + wid): V = X@Wv
// with X-hi staged in a dedicated 16 KB buffer, ISSUE-EARLY next-chunk X
// prefetch. V^T consumed in two 128-col halves through a 32 KB buffer.
// Phase 2: out = A(bf16) @ V.
// ---------------------------------------------------------------------------
__global__ __launch_bounds__(512) void av_kernel(
    const float* __restrict__ x, const unsigned short* __restrict__ wvf,
    const unsigned short* __restrict__ Abf, float* __restrict__ out) {
  __shared__ alignas(16) unsigned short xa[Nv * KSv];    // 16 KB X-hi stage
  __shared__ alignas(16) unsigned short vth[Nv * Nv];    // 32 KB V^T half
  const int bt = blockIdx.x;
  const float* __restrict__ X = x + (size_t)bt * (Nv * P2v);
  const unsigned short* __restrict__ Ab = Abf + (size_t)bt * (Nv * Nv);
  float* __restrict__ ob = out + (size_t)bt * (Nv * P2v);
  const int tid = threadIdx.x, lane = tid & 63, wid = tid >> 6;
  const int lg = lane >> 4, lr = lane & 15;
  const int r0 = wid * 16;

  // Preload A fragments (bf16, 4 x 16B per lane) — used in phase 2 only.
  bf8 af[4];
#pragma unroll
  for (int kt = 0; kt < 4; ++kt) {
    af[kt] = *(const bf8*)(Ab + (r0 + lr) * Nv + kt * 32 + lg * 8);
  }

  const f4 zero = {0.f, 0.f, 0.f, 0.f};
  f4 aV[16];  // [h*8 + rt] : ntile = h*8 + wid
#pragma unroll
  for (int n = 0; n < 16; ++n) aV[n] = zero;

  const int srow = tid >> 4;       // 0..31
  const int sp = (tid & 15) * 4;   // 0..60
  const float* __restrict__ Xrow = X + srow * P2v + sp;

  // Prologue: prefetch chunk 0 (4 rows x float4 per thread)
  float4 pf0 = *(const float4*)(Xrow);
  float4 pf1 = *(const float4*)(Xrow + 32 * P2v);
  float4 pf2 = *(const float4*)(Xrow + 64 * P2v);
  float4 pf3 = *(const float4*)(Xrow + 96 * P2v);

  for (int c = 0; c < 4; ++c) {
    ushort4 q0, q1, q2, q3;
    q0.x = f2bf(pf0.x); q0.y = f2bf(pf0.y); q0.z = f2bf(pf0.z); q0.w = f2bf(pf0.w);
    q1.x = f2bf(pf1.x); q1.y = f2bf(pf1.y); q1.z = f2bf(pf1.z); q1.w = f2bf(pf1.w);
    q2.x = f2bf(pf2.x); q2.y = f2bf(pf2.y); q2.z = f2bf(pf2.z); q2.w = f2bf(pf2.w);
    q3.x = f2bf(pf3.x); q3.y = f2bf(pf3.y); q3.z = f2bf(pf3.z); q3.w = f2bf(pf3.w);

    __syncthreads();  // previous chunk's reads complete before overwrite
    *(ushort4*)(xa + swz64(srow, sp)) = q0;
    *(ushort4*)(xa + swz64(srow + 32, sp)) = q1;
    *(ushort4*)(xa + swz64(srow + 64, sp)) = q2;
    *(ushort4*)(xa + swz64(srow + 96, sp)) = q3;

    if (c < 3) {  // issue-early next chunk
      pf0 = *(const float4*)(Xrow + (c + 1) * 64);
      pf1 = *(const float4*)(Xrow + (c + 1) * 64 + 32 * P2v);
      pf2 = *(const float4*)(Xrow + (c + 1) * 64 + 64 * P2v);
      pf3 = *(const float4*)(Xrow + (c + 1) * 64 + 96 * P2v);
    }
    __syncthreads();
#pragma unroll
    for (int ktl = 0; ktl < 2; ++ktl) {
      const int kt = c * 2 + ktl;
#pragma unroll
      for (int h = 0; h < 2; ++h) {
        const int ntile = h * 8 + wid;
        const int o = ((kt * 16 + ntile) * 64 + lane) * 8;
        const bf8 fv = *(const bf8*)(wvf + o);
#pragma unroll
        for (int rt = 0; rt < 8; ++rt) {
          const bf8 xh =
              *(const bf8*)(xa + swz64(rt * 16 + lr, ktl * 32 + lg * 8));
          aV[h * 8 + rt] = MFMA16(xh, fv, aV[h * 8 + rt]);
        }
      }
    }
  }

  // Two halves: write V^T half (local rows 0..127), sync, A@V, out cols half.
#pragma unroll
  for (int h = 0; h < 2; ++h) {
    if (h == 1) __syncthreads();  // half-0 reads done before overwrite
    const int ql = wid * 16 + lr;
#pragma unroll
    for (int rt = 0; rt < 8; ++rt) {
      const int j0 = rt * 16 + 4 * lg;
      ushort4 pk;
      pk.x = f2bf(aV[h * 8 + rt][0]);
      pk.y = f2bf(aV[h * 8 + rt][1]);
      pk.z = f2bf(aV[h * 8 + rt][2]);
      pk.w = f2bf(aV[h * 8 + rt][3]);
      *(ushort4*)(vth + swz128(ql, j0)) = pk;
    }
    __syncthreads();

    f4 aO[8];
#pragma unroll
    for (int n = 0; n < 8; ++n) aO[n] = zero;
#pragma unroll
    for (int kt = 0; kt < 4; ++kt) {
#pragma unroll
      for (int n = 0; n < 8; ++n) {
        const bf8 vf =
            *(const bf8*)(vth + swz128(n * 16 + lr, kt * 32 + lg * 8));
        aO[n] = MFMA16(af[kt], vf, aO[n]);
      }
    }
#pragma unroll
    for (int n = 0; n < 8; ++n) {
#pragma unroll
      for (int rr = 0; rr < 4; ++rr) {
        ob[(r0 + 4 * lg + rr) * P2v + h * 128 + n * 16 + lr] = aO[n][rr];
      }
    }
  }
}

extern "C" void kernel_launch(void* const* d_in, const int* in_sizes, int n_in,
                              void* d_out, int out_size, void* d_ws,
                              size_t ws_size, hipStream_t stream) {
  const float* x = (const float*)d_in[0];
  const float* Wq = (const float*)d_in[1];
  const float* Wk = (const float*)d_in[2];
  const float* Wv = (const float*)d_in[3];
  float* out = (float*)d_out;

  // ws: W frags (256 KB) | S fp32 (33.55 MB) | A bf16 (16.78 MB) = 50.6 MB
  unsigned short* wqh = (unsigned short*)d_ws;
  unsigned short* wql = wqh + 16384;
  unsigned short* wkh = wql + 16384;
  unsigned short* wkl = wkh + 16384;
  unsigned short* wvf = wkl + 16384;  // 65536 elems
  float* S = (float*)((char*)d_ws + 262144);
  unsigned short* Abf = (unsigned short*)((char*)d_ws + 262144 + 33554432);

  hipLaunchKernelGGL(prep_w_kernel, dim3(384), dim3(256), 0, stream, Wq, Wk,
                     Wv, wqh, wql, wkh, wkl, wvf);
  hipLaunchKernelGGL(qk_kernel, dim3(Bv * Tv), dim3(512), 0, stream, x, wqh,
                     wql, wkh, wkl, S);
  hipLaunchKernelGGL(softmax_t_kernel, dim3(Bv * Nv * Nv / 256), dim3(256), 0,
                     stream, S, Abf);
  hipLaunchKernelGGL(av_kernel, dim3(Bv * Tv), dim3(512), 0, stream, x, wvf,
                     Abf, out);
}